// Round 5
// baseline (1927.433 us; speedup 1.0000x reference)
//
#include <hip/hip_runtime.h>
#include <hip/hip_bf16.h>
#include <stdint.h>
#include <string.h>

#define HIDDEN 1024
#define FEAT   512
#define PREV   10
#define PRED   20
#define BATCH  1024
#define KTOT   (HIDDEN + FEAT)   // 1536
#define N4H    4096
#define TSTEPS (PREV + PRED)     // 30
#define NBLK   512               // 2 blocks/CU on 256 CUs
#define NTHR   512

typedef __attribute__((ext_vector_type(8))) short short8;
typedef __attribute__((ext_vector_type(4))) float f32x4;
typedef unsigned long long ull;

// ---- async global->LDS 16B copy (wave-uniform LDS base + lane*16), plain-cached ----
typedef __attribute__((address_space(3))) unsigned int u32_lds;
typedef const __attribute__((address_space(1))) unsigned int u32_gbl;

__device__ __forceinline__ void async16(void* lds, const void* g) {
  u32_lds* lp = (u32_lds*)(unsigned int)(uintptr_t)lds;
  u32_gbl* gp = (u32_gbl*)(uintptr_t)g;
  __builtin_amdgcn_global_load_lds(gp, lp, 16, 0, 0);
}

__device__ __forceinline__ float sigmoidf_(float x) {
  return 1.0f / (1.0f + __expf(-x));
}
__device__ __forceinline__ float tanhf_(float x) {
  return 1.0f - 2.0f / (1.0f + __expf(2.0f * x));
}

// device-coherent (LLC) load/store — bypass the non-coherent L1/L2
__device__ __forceinline__ ull cload(const void* p) {
  return __hip_atomic_load((const ull*)p, __ATOMIC_RELAXED, __HIP_MEMORY_SCOPE_AGENT);
}
__device__ __forceinline__ void cstore(void* p, ull v) {
  __hip_atomic_store((ull*)p, v, __ATOMIC_RELAXED, __HIP_MEMORY_SCOPE_AGENT);
}
__device__ __forceinline__ void cstore4(void* p, unsigned v) {
  __hip_atomic_store((unsigned*)p, v, __ATOMIC_RELAXED, __HIP_MEMORY_SCOPE_AGENT);
}

// ---- pack [Wh;Wx] (fp32, [K,4096] gate-blocked) -> WpT (bf16, [4096,K], gate-interleaved n=4j+g) ----
__global__ void pack_w_kernel(const float* __restrict__ Wx, const float* __restrict__ Wh,
                              __hip_bfloat16* __restrict__ WpT) {
  __shared__ float tile[64][65];
  const int k0 = blockIdx.x * 64, n0 = blockIdx.y * 64;
  const int tid = threadIdx.x;
  const float* src = (k0 < HIDDEN) ? (Wh + (size_t)k0 * N4H) : (Wx + (size_t)(k0 - HIDDEN) * N4H);
  {
    const int jl = tid & 15, g = (tid >> 4) & 3, klb = tid >> 6;
#pragma unroll
    for (int it = 0; it < 16; ++it) {
      int kl = klb + it * 4;
      tile[kl][4 * jl + g] = src[(size_t)kl * N4H + g * HIDDEN + (n0 >> 2) + jl];
    }
  }
  __syncthreads();
  {
    const int kl = tid & 63, nlb = tid >> 6;
#pragma unroll
    for (int it = 0; it < 16; ++it) {
      int nl = nlb + it * 4;
      WpT[(size_t)(n0 + nl) * KTOT + k0 + kl] = __float2bfloat16(tile[kl][nl]);
    }
  }
}

__global__ void pack_bias_kernel(const float* __restrict__ b, float* __restrict__ bp) {
  int n = blockIdx.x * 256 + threadIdx.x;
  if (n < N4H) bp[n] = b[(n & 3) * HIDDEN + (n >> 2)];
}

// ---- convert inputs fp32 -> bf16 ----
__global__ void cvt_x_kernel(const float* __restrict__ xr, const float* __restrict__ xf,
                             __hip_bfloat16* __restrict__ xrb, __hip_bfloat16* __restrict__ xfb) {
  const int NR4 = BATCH * TSTEPS * FEAT / 4;
  const int NF4 = BATCH * PRED * FEAT / 4;
  int i = blockIdx.x * 256 + threadIdx.x;
  float4 v;
  __hip_bfloat16* dst;
  if (i < NR4) {
    v = ((const float4*)xr)[i];
    dst = xrb + (size_t)i * 4;
  } else {
    int j = i - NR4;
    if (j >= NF4) return;
    v = ((const float4*)xf)[j];
    dst = xfb + (size_t)j * 4;
  }
  dst[0] = __float2bfloat16(v.x);
  dst[1] = __float2bfloat16(v.y);
  dst[2] = __float2bfloat16(v.z);
  dst[3] = __float2bfloat16(v.w);
}

// ---- one timestep: MT x 128 GEMM (double-buffered, pipelined) + fused gates ----
// MT=64 (prefix) or MT=128 (main). 512 threads = 8 waves; wave tile (MT/2) x 32.
template <int MT>
__device__ __forceinline__ void do_step(
    const unsigned short* __restrict__ hcur, unsigned short* __restrict__ hnext,
    const unsigned short* __restrict__ xrb, const unsigned short* __restrict__ xfb,
    const unsigned short* __restrict__ wp_us, const float* __restrict__ biasp,
    const float* __restrict__ w2, float* __restrict__ cbuf,
    float* __restrict__ accout, float* __restrict__ creg, char* smem,
    int t, int r0, int r0a, int nt,
    int tid, int w, int l, int sub, int csrc, int quad, int lrow) {

  const int n0 = nt * 128;
  constexpr int NK = KTOT / 64;        // 24
  constexpr int AM = MT / 32;          // af frags: 4 (MT=128) / 2 (MT=64)
  constexpr int AIT = MT / 64;         // A 64-row groups: 2 / 1
  const int wm = w & 1, wn = w >> 1;   // wave tile: rows wm*(MT/2), cols wn*32
  const int mbase = wm * (MT / 2);
  const int arow = w * 8 + sub;

  char* sA[2] = {smem, smem + 16384};
  char* sB[2] = {smem + 32768, smem + 49152};

  f32x4 acc[AM][2];
#pragma unroll
  for (int a = 0; a < AM; ++a) {
    acc[a][0] = (f32x4){0.f, 0.f, 0.f, 0.f};
    acc[a][1] = (f32x4){0.f, 0.f, 0.f, 0.f};
  }

  const unsigned short* xbase;
  size_t xstr;
  if (r0 < BATCH) {
    xbase = xrb + ((size_t)r0 * TSTEPS + t) * FEAT;
    xstr = (size_t)TSTEPS * FEAT;
  } else {
    xbase = xfb + ((size_t)(r0 - BATCH) * PRED + (t - PREV)) * FEAT;
    xstr = (size_t)PRED * FEAT;
  }

  ull ar[AIT][2];  // coherent h prefetch (registers)

  // ---- prologue: stage kt=0 (h range) ----
  {
    const unsigned short* bb = wp_us + (size_t)n0 * KTOT;
#pragma unroll
    for (int it = 0; it < 2; ++it)
      async16(sB[0] + (it * 64 + w * 8) * 128, bb + (size_t)(it * 64 + arow) * KTOT + csrc * 8);
#pragma unroll
    for (int it = 0; it < AIT; ++it) {
      const unsigned short* ap = hcur + (size_t)(r0a + it * 64 + arow) * HIDDEN + csrc * 8;
      ar[it][0] = cload(ap);
      ar[it][1] = cload(ap + 4);
    }
  }

#pragma unroll 1
  for (int kt = 0; kt < NK; ++kt) {
    const int p = kt & 1, pn = p ^ 1;
    const int k0 = kt * 64;
    const bool hk = (k0 < HIDDEN);
    __syncthreads();  // stage(kt) landed (vmcnt drain); MFMA(kt-1) LDS reads done
    if (hk) {
#pragma unroll
      for (int it = 0; it < AIT; ++it) {
        ull* lw = (ull*)(sA[p] + (it * 64 + arow) * 128 + (l & 7) * 16);
        lw[0] = ar[it][0];
        lw[1] = ar[it][1];
      }
      __syncthreads();  // publish A to the block (no pending asyncs here -> cheap)
    }
    // issue stage(kt+1) into the other buffer; drains only at NEXT iter's barrier
    if (kt + 1 < NK) {
      const int k1 = k0 + 64;
      const unsigned short* bb = wp_us + (size_t)n0 * KTOT + k1;
#pragma unroll
      for (int it = 0; it < 2; ++it)
        async16(sB[pn] + (it * 64 + w * 8) * 128, bb + (size_t)(it * 64 + arow) * KTOT + csrc * 8);
      if (k1 < HIDDEN) {
#pragma unroll
        for (int it = 0; it < AIT; ++it) {
          const unsigned short* ap = hcur + (size_t)(r0a + it * 64 + arow) * HIDDEN + k1 + csrc * 8;
          ar[it][0] = cload(ap);
          ar[it][1] = cload(ap + 4);
        }
      } else {
#pragma unroll
        for (int it = 0; it < AIT; ++it)
          async16(sA[pn] + (it * 64 + w * 8) * 128,
                  xbase + (size_t)(it * 64 + arow) * xstr + (k1 - HIDDEN) + csrc * 8);
      }
    }
    // compute kt (overlaps with in-flight stage(kt+1))
#pragma unroll
    for (int kk = 0; kk < 2; ++kk) {
      const int swz = (((kk << 2) + quad) ^ (lrow & 7)) * 16;
      short8 af[AM], bf[2];
#pragma unroll
      for (int mi = 0; mi < AM; ++mi)
        af[mi] = *(const short8*)(sA[p] + (mbase + mi * 16 + lrow) * 128 + swz);
#pragma unroll
      for (int ni = 0; ni < 2; ++ni)
        bf[ni] = *(const short8*)(sB[p] + (wn * 32 + ni * 16 + lrow) * 128 + swz);
#pragma unroll
      for (int mi = 0; mi < AM; ++mi)
#pragma unroll
        for (int ni = 0; ni < 2; ++ni)
          acc[mi][ni] = __builtin_amdgcn_mfma_f32_16x16x32_bf16(af[mi], bf[ni], acc[mi][ni], 0, 0, 0);
    }
  }
  __syncthreads();  // all LDS reads done; safe to overlay z

  // ---- epilogue: two 64-col passes; z MT x 64 f32 (stride 68) overlays staging ----
  float* zb = (float*)smem;
  const int kout = t - PREV;
  constexpr int JT = (MT == 128) ? 4 : 2;               // j per thread per pass
  const int row_e = (MT == 128) ? (tid >> 2) : (tid >> 3);
  const int jq = (MT == 128) ? (tid & 3) : (tid & 7);
#pragma unroll 1
  for (int h2 = 0; h2 < 2; ++h2) {
    if ((wn >> 1) == h2) {
      const int cb = (wn & 1) * 32;
#pragma unroll
      for (int mi = 0; mi < AM; ++mi)
#pragma unroll
        for (int ni = 0; ni < 2; ++ni) {
          f32x4 v = acc[mi][ni];
          const int col = cb + ni * 16 + lrow;
          const int rb = mbase + mi * 16 + quad * 4;
#pragma unroll
          for (int r = 0; r < 4; ++r) zb[(rb + r) * 68 + col] = v[r];
        }
    }
    __syncthreads();
    unsigned short hs[JT];
    float cn[JT];
    float psum = 0.f;
#pragma unroll
    for (int it = 0; it < JT; ++it) {
      const int jloc = jq * JT + it;
      float4 z4 = *(float4*)&zb[row_e * 68 + jloc * 4];
      float4 bi = *(const float4*)&biasp[n0 + h2 * 64 + jloc * 4];
      const int jg = nt * 32 + h2 * 16 + jloc;
      float gi = sigmoidf_(z4.x + bi.x);
      float gf = sigmoidf_(z4.y + bi.y);
      float gg = tanhf_(z4.z + bi.z);
      float go = sigmoidf_(z4.w + bi.w);
      const int ci = h2 * JT + it;
      float cnew = gf * creg[ci] + gi * gg;
      float hnew = go * tanhf_(cnew);
      creg[ci] = cnew;
      cn[it] = cnew;
      __hip_bfloat16 hbv = __float2bfloat16(hnew);
      hs[it] = *(unsigned short*)&hbv;
      if (MT == 128) psum += hnew * w2[jg];
    }
    const int rg = r0 + row_e;
    const int jg0 = nt * 32 + h2 * 16 + jq * JT;
    if (MT == 128) {
      ull hp;
      memcpy(&hp, hs, 8);
      cstore(&hnext[(size_t)rg * HIDDEN + jg0], hp);
      psum += __shfl_down(psum, 2, 4);
      psum += __shfl_down(psum, 1, 4);
      if ((tid & 3) == 0) atomicAdd(&accout[rg * PRED + kout], psum);
    } else {
      unsigned hp;
      memcpy(&hp, hs, 4);
      cstore4(&hnext[(size_t)rg * HIDDEN + jg0], hp);
      if (t == PREV - 1) {
        ull cp_;
        memcpy(&cp_, cn, 8);
        cstore(&cbuf[(size_t)rg * HIDDEN + jg0], cp_);
      }
    }
    __syncthreads();
  }
}

// ---- persistent LSTM: all 30 steps in one cooperative dispatch ----
// 512 blocks x 512 thr. nt = bid&31 (128 n-cols, weight slice L2-resident),
// rt = bid>>5. Prefix: M=64 rows (all blocks active, rows [0,1024)); main:
// M=128 rows of 2048. c in registers; handoff via cbuf at t=9->10.
__global__ __launch_bounds__(512, 4)
void lstm_persistent(const __hip_bfloat16* __restrict__ xrb,
                     const __hip_bfloat16* __restrict__ xfb,
                     const __hip_bfloat16* __restrict__ WpT,
                     const float* __restrict__ biasp,
                     const float* __restrict__ w2,
                     __hip_bfloat16* __restrict__ hb0,
                     __hip_bfloat16* __restrict__ hb1,
                     float* __restrict__ cbuf,
                     float* __restrict__ accout,
                     unsigned* __restrict__ bar) {
  __shared__ __align__(16) char smem[65536];  // A 16K x2 | B 16K x2 ; z overlays
  const int tid = threadIdx.x;
  const int bid = blockIdx.x;
  const int nt = bid & 31, rt = bid >> 5;
  const int w = tid >> 6, l = tid & 63;
  const int sub = l >> 3;
  const int csrc = (l & 7) ^ sub;  // XOR-swizzled 16B source column
  const int quad = l >> 4, lrow = l & 15;
  unsigned* cnt = bar;
  unsigned* flag = bar + 32;

  const unsigned short* wp_us = (const unsigned short*)WpT;
  float creg[8] = {0.f, 0.f, 0.f, 0.f, 0.f, 0.f, 0.f, 0.f};

#pragma unroll 1
  for (int t = 0; t < TSTEPS; ++t) {
    const unsigned short* hcur = (const unsigned short*)((t & 1) ? hb1 : hb0);
    unsigned short* hnext = (unsigned short*)((t & 1) ? hb0 : hb1);

    if (t < PREV) {
      const int r0 = rt * 64;  // rows [0,1024), all 512 blocks active
      do_step<64>(hcur, hnext, (const unsigned short*)xrb, (const unsigned short*)xfb,
                  wp_us, biasp, w2, cbuf, accout, creg, smem,
                  t, r0, r0, nt, tid, w, l, sub, csrc, quad, lrow);
    } else {
      const int r0 = rt * 128;  // rows [0,2048)
      if (t == PREV) {
        // mapping changed (M=64 -> M=128): reload cell state from cbuf (t=9, coherent)
        const int row_e = tid >> 2, jq = tid & 3;
        const int r0c = (r0 >= BATCH) ? r0 - BATCH : r0;
#pragma unroll
        for (int h2 = 0; h2 < 2; ++h2) {
          size_t base = (size_t)(r0c + row_e) * HIDDEN + nt * 32 + h2 * 16 + jq * 4;
          ull d0 = cload(&cbuf[base]);
          ull d1 = cload(&cbuf[base + 2]);
          float2 f0 = *(float2*)&d0, f1 = *(float2*)&d1;
          creg[h2 * 4 + 0] = f0.x;
          creg[h2 * 4 + 1] = f0.y;
          creg[h2 * 4 + 2] = f1.x;
          creg[h2 * 4 + 3] = f1.y;
        }
      }
      const int r0a = (t == PREV && r0 >= BATCH) ? r0 - BATCH : r0;
      do_step<128>(hcur, hnext, (const unsigned short*)xrb, (const unsigned short*)xfb,
                   wp_us, biasp, w2, cbuf, accout, creg, smem,
                   t, r0, r0a, nt, tid, w, l, sub, csrc, quad, lrow);
    }

    // ---- grid barrier: relaxed poll, no cache-invalidating fences ----
    if (t < TSTEPS - 1) {
      __syncthreads();  // per-wave vmcnt(0) drain precedes s_barrier
      if (tid == 0) {
        unsigned ph = (unsigned)(t + 1);
        unsigned old = __hip_atomic_fetch_add(cnt, 1u, __ATOMIC_RELAXED, __HIP_MEMORY_SCOPE_AGENT);
        if (old == NBLK - 1) {
          __hip_atomic_store(cnt, 0u, __ATOMIC_RELAXED, __HIP_MEMORY_SCOPE_AGENT);
          __hip_atomic_store(flag, ph, __ATOMIC_RELAXED, __HIP_MEMORY_SCOPE_AGENT);
        } else {
          while (__hip_atomic_load(flag, __ATOMIC_RELAXED, __HIP_MEMORY_SCOPE_AGENT) < ph)
            __builtin_amdgcn_s_sleep(4);
        }
      }
      __syncthreads();
    }
  }
}

// ---- final tanh chain over the 40960 fused dots ----
__global__ void final_kernel(const float* __restrict__ accout, const float* __restrict__ b2,
                             const float* __restrict__ w3, const float* __restrict__ b3,
                             const float* __restrict__ w4, const float* __restrict__ b4,
                             float* __restrict__ out) {
  int i = blockIdx.x * 256 + threadIdx.x;
  const int half = BATCH * PRED;
  if (i >= 2 * half) return;
  int r, k;
  if (i < half) {
    r = i / PRED;
    k = i % PRED;
  } else {
    r = BATCH + (i - half) / PRED;
    k = (i - half) % PRED;
  }
  float x = tanhf_(accout[r * PRED + k] + b2[0]);
  x = tanhf_(x * w3[0] + b3[0]);
  x = tanhf_(x * w4[0] + b4[0]);
  out[i] = x;
}

extern "C" void kernel_launch(void* const* d_in, const int* in_sizes, int n_in,
                              void* d_out, int out_size, void* d_ws, size_t ws_size,
                              hipStream_t stream) {
  const float* real_input = (const float*)d_in[0];
  const float* fake_input = (const float*)d_in[1];
  const float* Wx = (const float*)d_in[2];
  const float* Wh = (const float*)d_in[3];
  const float* b  = (const float*)d_in[4];
  const float* w2 = (const float*)d_in[5];
  const float* b2 = (const float*)d_in[6];
  const float* w3 = (const float*)d_in[7];
  const float* b3 = (const float*)d_in[8];
  const float* w4 = (const float*)d_in[9];
  const float* b4 = (const float*)d_in[10];
  float* out = (float*)d_out;

  char* ws = (char*)d_ws;
  size_t off = 0;
  __hip_bfloat16* WpT = (__hip_bfloat16*)(ws + off);  off += (size_t)N4H * KTOT * 2;
  float* biasp = (float*)(ws + off);                  off += (size_t)N4H * 4;
  __hip_bfloat16* xrb = (__hip_bfloat16*)(ws + off);  off += (size_t)BATCH * TSTEPS * FEAT * 2;
  __hip_bfloat16* xfb = (__hip_bfloat16*)(ws + off);  off += (size_t)BATCH * PRED * FEAT * 2;
  __hip_bfloat16* hb0 = (__hip_bfloat16*)(ws + off);  off += (size_t)2 * BATCH * HIDDEN * 2;
  __hip_bfloat16* hb1 = (__hip_bfloat16*)(ws + off);  off += (size_t)2 * BATCH * HIDDEN * 2;
  float* cbuf = (float*)(ws + off);                   off += (size_t)BATCH * HIDDEN * 4;
  float* accout = (float*)(ws + off);                 off += (size_t)2 * BATCH * PRED * 4;
  unsigned* bar = (unsigned*)(ws + off);              off += 256;

  hipMemsetAsync(hb0, 0, (size_t)2 * BATCH * HIDDEN * 2, stream);
  hipMemsetAsync(accout, 0, (size_t)2 * BATCH * PRED * 4, stream);
  hipMemsetAsync(bar, 0, 256, stream);

  pack_w_kernel<<<dim3(KTOT / 64, N4H / 64), 256, 0, stream>>>(Wx, Wh, WpT);
  pack_bias_kernel<<<N4H / 256, 256, 0, stream>>>(b, biasp);
  {
    int n4 = BATCH * TSTEPS * FEAT / 4 + BATCH * PRED * FEAT / 4;
    cvt_x_kernel<<<(n4 + 255) / 256, 256, 0, stream>>>(real_input, fake_input, xrb, xfb);
  }

  {
    const __hip_bfloat16* a_xrb = xrb;
    const __hip_bfloat16* a_xfb = xfb;
    const __hip_bfloat16* a_WpT = WpT;
    const float* a_biasp = biasp;
    const float* a_w2 = w2;
    __hip_bfloat16* a_hb0 = hb0;
    __hip_bfloat16* a_hb1 = hb1;
    float* a_cbuf = cbuf;
    float* a_acc = accout;
    unsigned* a_bar = bar;
    void* args[10] = {&a_xrb, &a_xfb, &a_WpT, &a_biasp, &a_w2,
                      &a_hb0, &a_hb1, &a_cbuf, &a_acc, &a_bar};
    hipError_t e = hipLaunchCooperativeKernel((const void*)lstm_persistent,
                                              dim3(NBLK), dim3(NTHR), args, 0, stream);
    if (e != hipSuccess) {
      // co-residency fallback: 512 blocks at 64 KB LDS / <=128 VGPR are 2/CU resident
      lstm_persistent<<<dim3(NBLK), dim3(NTHR), 0, stream>>>(
          xrb, xfb, WpT, biasp, w2, hb0, hb1, cbuf, accout, bar);
    }
  }

  final_kernel<<<(2 * BATCH * PRED + 255) / 256, 256, 0, stream>>>(accout, b2, w3, b3, w4, b4, out);
}